// Round 11
// baseline (161.035 us; speedup 1.0000x reference)
//
#include <hip/hip_runtime.h>
#include <hip/hip_bf16.h>

#define N_NODES 20000
#define MPAD    20096
#define E_EDGES 400000
#define LATENT 128
#define H1 256
#define HIDDEN 512
#define OUT_D 64
#define HEADS 4
#define NEG_SLOPE 0.2f
// fixed-pitch adjacency: deg ~ Binomial(400k, 1/20k) -> mean 20, sigma 4.47; 80 slots = 13+ sigma.
#define MAX_IN 80

// SESSION LESSONS (do not re-try):
//  R2:  global f32 atomicAdd accumulation -> 100 us memory-side serialization. Recompute instead.
//  R6:  hipLaunchCooperativeKernel is silently rejected under the harness's graph capture.
//  R7:  manual grid barrier (agent-scope acquire spin + threadfence) -> per-XCD L2 invalidation
//       storm: FETCH 9->84 MB, 62->485 us. Dispatch boundaries are CHEAPER than in-kernel grid
//       sync on gfx950. 3-dispatch structure is the floor.
//  R9:  persistent scatter (140 blocks = free co-residency slots) + u16 adj.
//  R10: sched_barrier(0) prefetch pinning = NULL (59.5 us unchanged). Prefetch sinking was not
//       the binding constraint. Remaining hypothesis: per-wave chain length x waves/SIMD.
//  R11 (this round): 8-wave MLP blocks (512 thr) — chain 288->144 MFMA steps, 3->6 waves/SIMD,
//       same LDS + same per-block weight traffic (isolates the chain/occupancy variable).

typedef __attribute__((ext_vector_type(8))) __bf16 bf16x8;
typedef __attribute__((ext_vector_type(4))) float f32x4;
typedef __attribute__((ext_vector_type(4))) unsigned short u16x4;
typedef __attribute__((ext_vector_type(8))) unsigned short u16x8;

__device__ __forceinline__ unsigned short f2bf(float f) {
    union { float f; unsigned int u; } v; v.f = f;
    unsigned int r = v.u + 0x7fffu + ((v.u >> 16) & 1u);  // RNE
    return (unsigned short)(r >> 16);
}
__device__ __forceinline__ float bf2f(unsigned short u) {
    union { unsigned int u; float f; } v; v.u = ((unsigned int)u) << 16;
    return v.f;
}

// ---------------- prep: LDS-tiled coalesced transpose-convert + cur zeroing -----------------------
#define W1_TILES 32
#define W2_TILES 128
#define WG_TILES 128
#define CUR_BLKS ((N_NODES + 255) / 256)   // 79
#define PREP_BLKS (W1_TILES + W2_TILES + WG_TILES + CUR_BLKS)
__global__ __launch_bounds__(256)
void prep_kernel(const float* __restrict__ W1, const float* __restrict__ W2,
                 const float* __restrict__ Wg,
                 unsigned short* __restrict__ W1t, unsigned short* __restrict__ W2t,
                 unsigned short* __restrict__ Wgt, int* __restrict__ cur) {
    int b = blockIdx.x;
    if (b >= W1_TILES + W2_TILES + WG_TILES) {
        int t = (b - (W1_TILES + W2_TILES + WG_TILES)) * 256 + threadIdx.x;
        if (t < N_NODES) cur[t] = 0;
        return;
    }
    const float* src; unsigned short* dst; int K, N, k0, n0;
    if (b < W1_TILES) {
        src = W1; dst = W1t; K = LATENT; N = H1;
        k0 = (b >> 3) * 32; n0 = (b & 7) * 32;
    } else if (b < W1_TILES + W2_TILES) {
        int t2 = b - W1_TILES;
        src = W2; dst = W2t; K = H1; N = HIDDEN;
        k0 = (t2 >> 4) * 32; n0 = (t2 & 15) * 32;
    } else {
        int t3 = b - W1_TILES - W2_TILES;
        src = Wg; dst = Wgt; K = HIDDEN; N = HEADS * OUT_D;
        k0 = (t3 >> 3) * 32; n0 = (t3 & 7) * 32;
    }
    __shared__ float tile[32][33];
    const int c = threadIdx.x & 31, r0 = threadIdx.x >> 5;
#pragma unroll
    for (int i = 0; i < 4; i++) {
        int r = r0 + i * 8;
        tile[r][c] = src[(size_t)(k0 + r) * N + n0 + c];       // coalesced read (c = n fast)
    }
    __syncthreads();
#pragma unroll
    for (int i = 0; i < 4; i++) {
        int r = r0 + i * 8;
        dst[(size_t)(n0 + r) * K + k0 + c] = f2bf(tile[c][r]); // coalesced write (c = k fast)
    }
}

// ---------------- merged: 8-wave MLP (blocks 0..627) || persistent scatter (140 blocks) -----------
#define TM 32
#define ZPITCH 136
#define XPITCH 264
#define X2PITCH 520
#define MLP_BLOCKS (MPAD / TM)                  // 628
#define SCAT_BLOCKS 140                         // 768 co-residency slots - 628 MLP blocks
__global__ __launch_bounds__(512, 6)
void mlp_scatter_kernel(const float* __restrict__ z,
                        const unsigned short* __restrict__ W1t,
                        const unsigned short* __restrict__ W2t,
                        const unsigned short* __restrict__ Wgt,
                        const float* __restrict__ b1, const float* __restrict__ b2,
                        const float* __restrict__ att_src, const float* __restrict__ att_dst,
                        const int* __restrict__ ei, int* __restrict__ cur,
                        unsigned short* __restrict__ adj,
                        unsigned short* __restrict__ hb,
                        float* __restrict__ a_src, float* __restrict__ a_dst) {
    __shared__ unsigned short x2s[TM * X2PITCH];   // 33.3 KB; first 8.7 KB aliased as zbf
    __shared__ unsigned short x1s[TM * XPITCH];    // 16.9 KB (50.2 KB total); aliased as red[] late

    if (blockIdx.x >= MLP_BLOCKS) {
        // persistent scatter: 140 blocks x 512 thr grid-stride all 400k edges (~5.6 edges/thread)
        int t0 = (blockIdx.x - MLP_BLOCKS) * 512 + threadIdx.x;
        for (int t = t0; t < E_EDGES; t += SCAT_BLOCKS * 512) {
            int s = ei[t], d = ei[E_EDGES + t];
            int idx = atomicAdd(&cur[d], 1);
            idx = min(idx, MAX_IN - 1);            // statistically unreachable clamp
            adj[d * MAX_IN + idx] = (unsigned short)s;   // node ids < 20000 < 65536
        }
        return;
    }

    unsigned short* zbf = x2s;
    const int tid = threadIdx.x;
    const int wave = tid >> 6, lane = tid & 63;    // 8 waves
    const int m0 = blockIdx.x * TM;
    const int fr = lane & 15, q = lane >> 4;

#define LDW1(kt, t) (*(const bf16x8*)(W1t + (size_t)(nb1 + (t) * 16 + fr) * LATENT + (kt) * 32 + q * 8))
#define LDW2(kt, t) (*(const bf16x8*)(W2t + (size_t)(nb2 + (t) * 16 + fr) * H1 + (kt) * 32 + q * 8))
#define LDW3(kt, t) (*(const bf16x8*)(Wgt + (size_t)(nb3 + (t) * 16 + fr) * HIDDEN + (kt) * 32 + q * 8))

    const int nb1 = wave * 32;      // layer-1 cols: 8 waves x 32 = 256
    const int nb2 = wave * 64;      // layer-2 cols: 8 waves x 64 = 512
    const int nb3 = wave * 32;      // layer-3 cols: 8 waves x 32 = 256

    bf16x8 w1a[2], w1b[2];
#pragma unroll
    for (int t = 0; t < 2; t++) w1a[t] = LDW1(0, t);

    {   // z staging: 512 threads x 8 floats = 32 rows x 128 cols
        const int r = tid >> 4, c0 = (tid & 15) * 8;
        const int zrow = min(m0 + r, N_NODES - 1);
        const float* zp = z + (size_t)zrow * LATENT + c0;
#pragma unroll
        for (int i = 0; i < 2; i++) {
            f32x4 v = *(const f32x4*)(zp + i * 4);
            u16x4 p = { f2bf(v[0]), f2bf(v[1]), f2bf(v[2]), f2bf(v[3]) };
            *(u16x4*)(zbf + r * ZPITCH + c0 + i * 4) = p;
        }
    }
    __syncthreads();

    // ---- layer 1: K=128 (4 kt), 4 MFMA/kt ----
    f32x4 acc1[2][2] = {};
#pragma unroll
    for (int kt = 0; kt < 4; kt++) {
        bf16x8* wc = (kt & 1) ? w1b : w1a;
        bf16x8* wn = (kt & 1) ? w1a : w1b;
        if (kt < 3) {
#pragma unroll
            for (int t = 0; t < 2; t++) wn[t] = LDW1(kt + 1, t);
        }
        bf16x8 af[2];
#pragma unroll
        for (int t = 0; t < 2; t++)
            af[t] = *(const bf16x8*)(zbf + (t * 16 + fr) * ZPITCH + kt * 32 + q * 8);
#pragma unroll
        for (int mt = 0; mt < 2; mt++)
#pragma unroll
            for (int nt = 0; nt < 2; nt++)
                acc1[mt][nt] = __builtin_amdgcn_mfma_f32_16x16x32_bf16(
                    wc[nt], af[mt], acc1[mt][nt], 0, 0, 0);
    }

    bf16x8 w2a[4], w2b[4];
#pragma unroll
    for (int t = 0; t < 4; t++) w2a[t] = LDW2(0, t);

    // layer-1 epilogue -> x1s
#pragma unroll
    for (int nt = 0; nt < 2; nt++) {
        const int n = nb1 + nt * 16 + q * 4;
        const f32x4 bv = *(const f32x4*)(b1 + n);
#pragma unroll
        for (int mt = 0; mt < 2; mt++) {
            u16x4 p;
#pragma unroll
            for (int r = 0; r < 4; r++) p[r] = f2bf(fmaxf(acc1[mt][nt][r] + bv[r], 0.f));
            *(u16x4*)(x1s + (mt * 16 + fr) * XPITCH + n) = p;
        }
    }
    __syncthreads();

    // ---- layer 2: K=256 (8 kt), single pass, 8 MFMA/kt ----
    f32x4 acc2[2][4] = {};
#pragma unroll
    for (int kt = 0; kt < 8; kt++) {
        bf16x8* wc = (kt & 1) ? w2b : w2a;
        bf16x8* wn = (kt & 1) ? w2a : w2b;
        if (kt < 7) {
#pragma unroll
            for (int t = 0; t < 4; t++) wn[t] = LDW2(kt + 1, t);
        }
        bf16x8 af[2];
#pragma unroll
        for (int t = 0; t < 2; t++)
            af[t] = *(const bf16x8*)(x1s + (t * 16 + fr) * XPITCH + kt * 32 + q * 8);
#pragma unroll
        for (int mt = 0; mt < 2; mt++)
#pragma unroll
            for (int nt = 0; nt < 4; nt++)
                acc2[mt][nt] = __builtin_amdgcn_mfma_f32_16x16x32_bf16(
                    wc[nt], af[mt], acc2[mt][nt], 0, 0, 0);
    }

    bf16x8 w3a[2], w3b[2];
#pragma unroll
    for (int t = 0; t < 2; t++) w3a[t] = LDW3(0, t);

    // layer-2 epilogue -> x2s
#pragma unroll
    for (int nt = 0; nt < 4; nt++) {
        const int n = nb2 + nt * 16 + q * 4;
        const f32x4 bv = *(const f32x4*)(b2 + n);
#pragma unroll
        for (int mt = 0; mt < 2; mt++) {
            u16x4 p;
#pragma unroll
            for (int r = 0; r < 4; r++) p[r] = f2bf(fmaxf(acc2[mt][nt][r] + bv[r], 0.f));
            *(u16x4*)(x2s + (mt * 16 + fr) * X2PITCH + n) = p;
        }
    }
    __syncthreads();                 // all x1s reads are complete after this barrier

    // ---- layer 3: K=512 (16 kt), 4 MFMA/kt + att epilogue ----
    f32x4 acc3[2][2] = {};
#pragma unroll
    for (int kt = 0; kt < 16; kt++) {
        bf16x8* wc = (kt & 1) ? w3b : w3a;
        bf16x8* wn = (kt & 1) ? w3a : w3b;
        if (kt < 15) {
#pragma unroll
            for (int t = 0; t < 2; t++) wn[t] = LDW3(kt + 1, t);
        }
        bf16x8 af[2];
#pragma unroll
        for (int t = 0; t < 2; t++)
            af[t] = *(const bf16x8*)(x2s + (t * 16 + fr) * X2PITCH + kt * 32 + q * 8);
#pragma unroll
        for (int mt = 0; mt < 2; mt++)
#pragma unroll
            for (int nt = 0; nt < 2; nt++)
                acc3[mt][nt] = __builtin_amdgcn_mfma_f32_16x16x32_bf16(
                    wc[nt], af[mt], acc3[mt][nt], 0, 0, 0);
    }

    {   // att epilogue: wave covers cols [wave*32, wave*32+32) = half of head (wave>>1)
        const int head = wave >> 1, half = wave & 1;
        f32x4 asv[2], adv[2];
#pragma unroll
        for (int nt = 0; nt < 2; nt++) {
            asv[nt] = *(const f32x4*)(att_src + head * OUT_D + half * 32 + nt * 16 + q * 4);
            adv[nt] = *(const f32x4*)(att_dst + head * OUT_D + half * 32 + nt * 16 + q * 4);
        }
        float* red = (float*)x1s;    // [32 rows][8 waves][2] = 2 KB, aliased into dead x1s
#pragma unroll
        for (int mt = 0; mt < 2; mt++) {
            const int row = m0 + mt * 16 + fr;
            float vs = 0.f, vd = 0.f;
#pragma unroll
            for (int nt = 0; nt < 2; nt++) {
                u16x4 p;
#pragma unroll
                for (int r = 0; r < 4; r++) {
                    float x = acc3[mt][nt][r];
                    p[r] = f2bf(x);
                    vs += x * asv[nt][r];
                    vd += x * adv[nt][r];
                }
                *(u16x4*)(hb + (size_t)row * (HEADS * OUT_D) + head * OUT_D + half * 32
                          + nt * 16 + q * 4) = p;
            }
            vs += __shfl_xor(vs, 16, 64); vs += __shfl_xor(vs, 32, 64);
            vd += __shfl_xor(vd, 16, 64); vd += __shfl_xor(vd, 32, 64);
            if (q == 0) {
                red[((mt * 16 + fr) * 8 + wave) * 2 + 0] = vs;
                red[((mt * 16 + fr) * 8 + wave) * 2 + 1] = vd;
            }
        }
        __syncthreads();
        // combine wave pairs: waves 0..3 finalize head=wave
        if (wave < HEADS) {
#pragma unroll
            for (int mt = 0; mt < 2; mt++) {
                const int row = m0 + mt * 16 + fr;
                if (q == 0 && row < N_NODES) {
                    const int ri = (mt * 16 + fr) * 8;
                    float vs = red[(ri + 2 * wave) * 2 + 0] + red[(ri + 2 * wave + 1) * 2 + 0];
                    float vd = red[(ri + 2 * wave) * 2 + 1] + red[(ri + 2 * wave + 1) * 2 + 1];
                    a_src[row * HEADS + wave] = vs;
                    a_dst[row * HEADS + wave] = vd;
                }
            }
        }
    }
#undef LDW1
#undef LDW2
#undef LDW3
}

// ---------------- single-pass gather-aggregate, adj broadcast via shfl (R5-proven, u16 adj) -------
__global__ __launch_bounds__(256)
void fused_gat(const unsigned short* __restrict__ adj, const int* __restrict__ cur,
               const float* __restrict__ a_src, const float* __restrict__ a_dst,
               const unsigned short* __restrict__ hb,
               const float* __restrict__ bias_g, float* __restrict__ out) {
    const int wave = threadIdx.x >> 6, lane = threadIdx.x & 63;
    const int grp = lane >> 5, sl = lane & 31;
    const int d = blockIdx.x * 8 + wave * 2 + grp;   // 2500 blocks x 8 nodes
    const int h = sl >> 3, j = sl & 7;
    const int cnt = min(cur[d], MAX_IN);
    const unsigned short* arow = adj + d * MAX_IN;
    const int gbase = grp * 32;                      // shfl source-lane base for this group

    // one coalesced adjacency load: lane sl holds edge sl (64 B per 32-lane group)
    int myadj = (sl < cnt) ? (int)arow[sl] : 0;

    const float ad = a_dst[d * HEADS + h];
    const unsigned short* hp = hb + h * OUT_D + j * 8;

    // self-loop seeds accumulators
    float vself = a_src[d * HEADS + h] + ad;
    vself = (vself > 0.f) ? vself : NEG_SLOPE * vself;
    float sm = __expf(fminf(vself, 60.f));
    u16x8 gs = *(const u16x8*)(hp + (size_t)d * (HEADS * OUT_D));
    float acc[8];
#pragma unroll
    for (int r = 0; r < 8; r++) acc[r] = sm * bf2f(gs[r]);

    const int lim = cnt < 32 ? cnt : 32;
    int e = 0;
    for (; e + 7 < lim; e += 8) {
        int sx[8]; float fx[8]; u16x8 gx[8];
#pragma unroll
        for (int u = 0; u < 8; u++) sx[u] = __shfl(myadj, gbase + e + u, 64);
#pragma unroll
        for (int u = 0; u < 8; u++) fx[u] = a_src[sx[u] * HEADS + h];
#pragma unroll
        for (int u = 0; u < 8; u++) gx[u] = *(const u16x8*)(hp + (size_t)sx[u] * (HEADS * OUT_D));
#pragma unroll
        for (int u = 0; u < 8; u++) {
            float v = fx[u] + ad;
            v = (v > 0.f) ? v : NEG_SLOPE * v;
            float w = __expf(fminf(v, 60.f));
            sm += w;
#pragma unroll
            for (int r = 0; r < 8; r++) acc[r] += w * bf2f(gx[u][r]);
        }
    }
    for (; e + 3 < lim; e += 4) {
        int sx[4]; float fx[4]; u16x8 gx[4];
#pragma unroll
        for (int u = 0; u < 4; u++) sx[u] = __shfl(myadj, gbase + e + u, 64);
#pragma unroll
        for (int u = 0; u < 4; u++) fx[u] = a_src[sx[u] * HEADS + h];
#pragma unroll
        for (int u = 0; u < 4; u++) gx[u] = *(const u16x8*)(hp + (size_t)sx[u] * (HEADS * OUT_D));
#pragma unroll
        for (int u = 0; u < 4; u++) {
            float v = fx[u] + ad;
            v = (v > 0.f) ? v : NEG_SLOPE * v;
            float w = __expf(fminf(v, 60.f));
            sm += w;
#pragma unroll
            for (int r = 0; r < 8; r++) acc[r] += w * bf2f(gx[u][r]);
        }
    }
    for (; e < lim; e++) {
        int s = __shfl(myadj, gbase + e, 64);
        float v = a_src[s * HEADS + h] + ad;
        v = (v > 0.f) ? v : NEG_SLOPE * v;
        float w = __expf(fminf(v, 60.f));
        u16x8 g = *(const u16x8*)(hp + (size_t)s * (HEADS * OUT_D));
        sm += w;
#pragma unroll
        for (int r = 0; r < 8; r++) acc[r] += w * bf2f(g[r]);
    }
    for (int e2 = 32; e2 < cnt; e2++) {   // rare (deg >= 32, ~0.3% of nodes)
        int s = arow[e2];
        float v = a_src[s * HEADS + h] + ad;
        v = (v > 0.f) ? v : NEG_SLOPE * v;
        float w = __expf(fminf(v, 60.f));
        u16x8 g = *(const u16x8*)(hp + (size_t)s * (HEADS * OUT_D));
        sm += w;
#pragma unroll
        for (int r = 0; r < 8; r++) acc[r] += w * bf2f(g[r]);
    }

    // per-head normalize, then mean over heads (shfl_xor 8/16 stays inside the 32-lane group)
    const float inv = 1.f / (sm + 1e-16f);
#pragma unroll
    for (int r = 0; r < 8; r++) {
        acc[r] *= inv;
        acc[r] += __shfl_xor(acc[r], 8, 64);
        acc[r] += __shfl_xor(acc[r], 16, 64);
    }
    if (h == 0) {
        const f32x4 bg0 = *(const f32x4*)(bias_g + j * 8);
        const f32x4 bg1 = *(const f32x4*)(bias_g + j * 8 + 4);
        f32x4 o0 = { 0.25f * acc[0] + bg0[0], 0.25f * acc[1] + bg0[1],
                     0.25f * acc[2] + bg0[2], 0.25f * acc[3] + bg0[3] };
        f32x4 o1 = { 0.25f * acc[4] + bg1[0], 0.25f * acc[5] + bg1[1],
                     0.25f * acc[6] + bg1[2], 0.25f * acc[7] + bg1[3] };
        *(f32x4*)(out + (size_t)d * OUT_D + j * 8) = o0;
        *(f32x4*)(out + (size_t)d * OUT_D + j * 8 + 4) = o1;
    }
}

extern "C" void kernel_launch(void* const* d_in, const int* in_sizes, int n_in,
                              void* d_out, int out_size, void* d_ws, size_t ws_size,
                              hipStream_t stream) {
    const float* z       = (const float*)d_in[0];
    const float* W1      = (const float*)d_in[1];
    const float* b1      = (const float*)d_in[2];
    const float* W2      = (const float*)d_in[3];
    const float* b2      = (const float*)d_in[4];
    const float* Wg      = (const float*)d_in[5];
    const float* att_src = (const float*)d_in[6];
    const float* att_dst = (const float*)d_in[7];
    const float* bias_g  = (const float*)d_in[8];
    const int*   ei      = (const int*)d_in[9];
    float* out = (float*)d_out;

    char* ws = (char*)d_ws;
    size_t off = 0;
    auto carve = [&](size_t bytes) { void* p = ws + off; off += (bytes + 255) & ~(size_t)255; return p; };

    unsigned short* W1t = (unsigned short*)carve((size_t)H1 * LATENT * 2);
    unsigned short* W2t = (unsigned short*)carve((size_t)HIDDEN * H1 * 2);
    unsigned short* Wgt = (unsigned short*)carve((size_t)(HEADS * OUT_D) * HIDDEN * 2);
    unsigned short* hb  = (unsigned short*)carve((size_t)MPAD * HEADS * OUT_D * 2);
    float* a_src = (float*)carve((size_t)N_NODES * HEADS * 4);
    float* a_dst = (float*)carve((size_t)N_NODES * HEADS * 4);
    int*   cur   = (int*)carve((size_t)N_NODES * 4);
    unsigned short* adj = (unsigned short*)carve((size_t)MAX_IN * N_NODES * 2);

    // 3 dispatches. R11: 8-wave MLP blocks (chain halved, waves/SIMD doubled).
    prep_kernel<<<PREP_BLKS, 256, 0, stream>>>(W1, W2, Wg, W1t, W2t, Wgt, cur);

    mlp_scatter_kernel<<<MLP_BLOCKS + SCAT_BLOCKS, 512, 0, stream>>>(
        z, W1t, W2t, Wgt, b1, b2, att_src, att_dst, ei, cur, adj, hb, a_src, a_dst);

    fused_gat<<<N_NODES / 8, 256, 0, stream>>>(
        adj, cur, a_src, a_dst, hb, bias_g, out);
}